// Round 5
// baseline (102.286 us; speedup 1.0000x reference)
//
#include <hip/hip_runtime.h>

#define B 4096
#define D 16
#define R 1024
#define NC 10
#define IC 170
#define NT 11            // n-tiles of 16 -> 176 padded cols
#define NP 176
#define KSPLIT 4
#define RPB (R / KSPLIT) // 256 rules per block
#define BT 16            // batch rows per block
#define GSP 192          // Gs (epilogue) padded row stride
#define TSTR 72          // prep transpose LDS row stride (bf16)

typedef __attribute__((ext_vector_type(8))) short short8;
typedef __attribute__((ext_vector_type(4))) float f32x4;

__device__ __forceinline__ unsigned short f2bf(float f) {
    unsigned u = __float_as_uint(f);
    return (unsigned short)((u + 0x7fffu + ((u >> 16) & 1u)) >> 16);  // RNE
}

// ---------------- K0: prep — pack rules, transpose-convert consequents to
// Bsw bf16 [176 cols][1024 k], zero y, write x_ext. One launch, 452 blocks.
__global__ __launch_bounds__(256) void prep_kernel(
    const float* __restrict__ cons, const int* __restrict__ rule_idx,
    const float* __restrict__ x, unsigned* __restrict__ packed,
    unsigned short* __restrict__ Bsw, float* __restrict__ out_y,
    float* __restrict__ out_xext)
{
    __shared__ unsigned short T[NP * TSTR];   // 25344 B (only used by blocks 0-15)
    const int blk = blockIdx.x, tid = threadIdx.x;

    if (blk < 16) {
        // k-tile of 64: coalesced read of cons[k][c], LDS transpose, 128B-row writes
        const int k0 = blk * 64;
        for (int t = tid; t < 64 * IC; t += 256) {
            int k = t / IC, c = t - k * IC;
            T[c * TSTR + k] = f2bf(cons[(size_t)(k0 + k) * IC + c]);
        }
        for (int t = tid; t < (NP - IC) * 64; t += 256) {   // zero pad cols 170..175
            int c = IC + t / 64, k = t & 63;
            T[c * TSTR + k] = 0;
        }
        __syncthreads();
        for (int t = tid; t < NP * 8; t += 256) {
            int row = t >> 3, seg = t & 7;
            *(short8*)&Bsw[(size_t)row * R + k0 + seg * 8] =
                *(const short8*)&T[row * TSTR + seg * 8];
        }
    } else if (blk < 20) {
        int r = (blk - 16) * 256 + tid;
        unsigned bits = 0;
#pragma unroll
        for (int d = 0; d < D; ++d)
            bits |= (((unsigned)rule_idx[d * R + r]) & 3u) << (2 * d);
        packed[r] = bits;
    } else if (blk < 180) {
        out_y[(blk - 20) * 256 + tid] = 0.0f;   // B*NC = 40960 = 160*256
    } else {
        int t = (blk - 180) * 256 + tid;        // B*17 = 69632 = 272*256
        int b = t / 17, i = t - b * 17;
        out_xext[t] = (i < 16) ? x[b * D + i] : 1.0f;
    }
}

// ---------------- K1: firing via quad tables (4 LDS gathers/rule)
__global__ __launch_bounds__(256) void firing_kernel(
    const float* __restrict__ x, const float* __restrict__ centers,
    const float* __restrict__ widths, const unsigned* __restrict__ packed,
    float* __restrict__ out_norm)
{
    __shared__ float s_z[64];
    __shared__ float s_z2[8][16];
    __shared__ float s_z4[4 * 256];
    __shared__ float s_red[8];
    const int b = blockIdx.x, tid = threadIdx.x;

    if (tid < 64) {
        int d = tid >> 2;
        float xv = x[b * D + d];
        float c = centers[tid], w = widths[tid];
        float diff = xv - c;
        s_z[tid] = 1e-9f - diff * diff / (2.0f * w * w);
    }
    __syncthreads();
    if (tid < 128) {   // pair tables: pair p = dims (2p, 2p+1)
        int p = tid >> 4, i = tid & 15;
        s_z2[p][i] = s_z[p * 8 + (i & 3)] + s_z[p * 8 + 4 + ((i >> 2) & 3)];
    }
    __syncthreads();
#pragma unroll
    for (int q = 0; q < 4; ++q)   // quad q = pairs (2q, 2q+1)
        s_z4[q * 256 + tid] = s_z2[2 * q][tid & 15] + s_z2[2 * q + 1][(tid >> 4) & 15];
    __syncthreads();

    float f[4], lsum = 0.0f;
#pragma unroll
    for (int j = 0; j < 4; ++j) {
        unsigned w = packed[tid + 256 * j];
        float s = s_z4[w & 255] + s_z4[256 + ((w >> 8) & 255)]
                + s_z4[512 + ((w >> 16) & 255)] + s_z4[768 + (w >> 24)];
        f[j] = __expf(s);
        lsum += f[j];
    }
#pragma unroll
    for (int off = 1; off < 64; off <<= 1) lsum += __shfl_xor(lsum, off, 64);
    const int lane = tid & 63, wid = tid >> 6;
    if (lane == 0) s_red[wid] = lsum;
    __syncthreads();
    if (tid == 0) {
        float tot = s_red[0] + s_red[1] + s_red[2] + s_red[3] + 1e-9f;
        s_red[4] = 1.0f / tot;
    }
    __syncthreads();
    const float inv = s_red[4];
#pragma unroll
    for (int j = 0; j < 4; ++j)
        out_norm[(size_t)b * R + tid + 256 * j] = f[j] * inv;
}

// ---------------- K2: MFMA GEMM, LDS-free K-loop. In the 16x16x32 layout each
// A/B element lives in exactly one lane -> load fragments straight from
// global (Bsw in L2, norm rows L1-shared across the block's 4 waves).
// No barriers in the K-loop; compiler pipelines 5 indep loads/k-step.
__global__ __launch_bounds__(256, 4) void yhat_kernel(
    const float* __restrict__ norm, const unsigned short* __restrict__ Bsw,
    const float* __restrict__ x, float* __restrict__ out_y)
{
    __shared__ float Gs[BT * GSP];   // 12 KiB
    __shared__ float xe[BT * 17];

    const int tid = threadIdx.x;
    const int mt = blockIdx.x & 255;
    const int ks = blockIdx.x >> 8;
    const int bl0 = mt * BT;
    const int r_base = ks * RPB;

    for (int t = tid; t < BT * 17; t += 256) {   // 272 > 256: strided loop!
        int bl = t / 17, i = t - bl * 17;
        xe[t] = (i < 16) ? x[(size_t)(bl0 + bl) * D + i] : 1.0f;
    }

    const int lane = tid & 63, wv = tid >> 6;
    const int m_ = lane & 15, q_ = lane >> 4;
    const int nt0 = wv * 3;
    const int ntn = (wv == 3) ? 2 : 3;

    f32x4 acc[3];
    const f32x4 zf = {0.f, 0.f, 0.f, 0.f};
    acc[0] = zf; acc[1] = zf; acc[2] = zf;

    const float* aptr = &norm[(size_t)(bl0 + m_) * R + r_base + q_ * 8];
    const unsigned short* bptr = &Bsw[(size_t)r_base + q_ * 8];

#pragma unroll
    for (int kk = 0; kk < RPB; kk += 32) {
        float4 a0 = *(const float4*)(aptr + kk);
        float4 a1 = *(const float4*)(aptr + kk + 4);
        short8 a;
        a[0] = (short)f2bf(a0.x); a[1] = (short)f2bf(a0.y);
        a[2] = (short)f2bf(a0.z); a[3] = (short)f2bf(a0.w);
        a[4] = (short)f2bf(a1.x); a[5] = (short)f2bf(a1.y);
        a[6] = (short)f2bf(a1.z); a[7] = (short)f2bf(a1.w);
#pragma unroll
        for (int j = 0; j < 3; ++j) {
            if (j < ntn) {
                int row = (nt0 + j) * 16 + m_;
                short8 bf = *(const short8*)&bptr[(size_t)row * R + kk];
                acc[j] = __builtin_amdgcn_mfma_f32_16x16x32_bf16(a, bf, acc[j], 0, 0, 0);
            }
        }
    }

    __syncthreads();   // xe ready + Gs free
#pragma unroll
    for (int j = 0; j < 3; ++j) {
        if (j < ntn) {
            int nt = nt0 + j;
#pragma unroll
            for (int r = 0; r < 4; ++r)
                Gs[(q_ * 4 + r) * GSP + nt * 16 + m_] = acc[j][r];  // C/D: col=lane&15, row=quad*4+reg
        }
    }
    __syncthreads();
    if (tid < BT * NC) {
        int bl = tid / NC, c = tid - bl * NC;
        float y = 0.0f;
#pragma unroll
        for (int i = 0; i < 17; ++i)
            y += xe[bl * 17 + i] * Gs[bl * GSP + i * NC + c];
        atomicAdd(&out_y[(size_t)(bl0 + bl) * NC + c], y);
    }
}

extern "C" void kernel_launch(void* const* d_in, const int* in_sizes, int n_in,
                              void* d_out, int out_size, void* d_ws, size_t ws_size,
                              hipStream_t stream) {
    const float* x        = (const float*)d_in[0];
    const float* centers  = (const float*)d_in[1];
    const float* widths   = (const float*)d_in[2];
    const float* cons     = (const float*)d_in[3];
    const int*   rule_idx = (const int*)d_in[4];

    float* out      = (float*)d_out;
    float* out_y    = out;                                  // (4096,10)
    float* out_norm = out + (size_t)B * NC;                 // (4096,1024)
    float* out_xext = out + (size_t)B * NC + (size_t)B * R; // (4096,17)

    unsigned* packed     = (unsigned*)d_ws;                          // 4 KB
    unsigned short* Bsw  = (unsigned short*)((char*)d_ws + 4096);    // 352 KB

    prep_kernel<<<452, 256, 0, stream>>>(cons, rule_idx, x, packed, Bsw, out_y, out_xext);
    firing_kernel<<<B, 256, 0, stream>>>(x, centers, widths, packed, out_norm);
    yhat_kernel<<<(B / BT) * KSPLIT, 256, 0, stream>>>(out_norm, Bsw, x, out_y);
}

// Round 6
// 96.619 us; speedup vs baseline: 1.0586x; 1.0586x over previous
//
#include <hip/hip_runtime.h>

#define B 4096
#define D 16
#define R 1024
#define NC 10
#define IC 170
#define NT 11            // n-tiles of 16 -> 176 padded cols
#define NP 176
#define KC 64            // k per LDS staging chunk
#define KSPLIT 4
#define RPB (R / KSPLIT) // 256 rules per block
#define BT 16            // batch rows per block
#define BSTR 72          // padded k-stride (bf16) for Bs/As
#define GSP 192          // Gs (epilogue) padded row stride
#define TSTR 72          // prep transpose LDS row stride (bf16)

typedef __attribute__((ext_vector_type(8))) short short8;
typedef __attribute__((ext_vector_type(4))) float f32x4;

__device__ __forceinline__ unsigned short f2bf(float f) {
    unsigned u = __float_as_uint(f);
    return (unsigned short)((u + 0x7fffu + ((u >> 16) & 1u)) >> 16);  // RNE
}

// ---------------- K0: prep — pack rules, coalesced transpose-convert of
// consequents to Bsw bf16 [176 cols][1024 k], zero y, write x_ext.
__global__ __launch_bounds__(256) void prep_kernel(
    const float* __restrict__ cons, const int* __restrict__ rule_idx,
    const float* __restrict__ x, unsigned* __restrict__ packed,
    unsigned short* __restrict__ Bsw, float* __restrict__ out_y,
    float* __restrict__ out_xext)
{
    __shared__ unsigned short T[NP * TSTR];   // 25344 B (blocks 0-15 only)
    const int blk = blockIdx.x, tid = threadIdx.x;

    if (blk < 16) {
        const int k0 = blk * 64;
        for (int t = tid; t < 64 * IC; t += 256) {
            int k = t / IC, c = t - k * IC;
            T[c * TSTR + k] = f2bf(cons[(size_t)(k0 + k) * IC + c]);
        }
        for (int t = tid; t < (NP - IC) * 64; t += 256) {   // zero pad cols 170..175
            int c = IC + t / 64, k = t & 63;
            T[c * TSTR + k] = 0;
        }
        __syncthreads();
        for (int t = tid; t < NP * 8; t += 256) {
            int row = t >> 3, seg = t & 7;
            *(short8*)&Bsw[(size_t)row * R + k0 + seg * 8] =
                *(const short8*)&T[row * TSTR + seg * 8];
        }
    } else if (blk < 20) {
        int r = (blk - 16) * 256 + tid;
        unsigned bits = 0;
#pragma unroll
        for (int d = 0; d < D; ++d)
            bits |= (((unsigned)rule_idx[d * R + r]) & 3u) << (2 * d);
        packed[r] = bits;
    } else if (blk < 180) {
        out_y[(blk - 20) * 256 + tid] = 0.0f;   // B*NC = 40960 = 160*256
    } else {
        int t = (blk - 180) * 256 + tid;        // B*17 = 69632 = 272*256
        int b = t / 17, i = t - b * 17;
        out_xext[t] = (i < 16) ? x[b * D + i] : 1.0f;
    }
}

// ---------------- K1: firing via quad tables (4 LDS gathers/rule)
__global__ __launch_bounds__(256) void firing_kernel(
    const float* __restrict__ x, const float* __restrict__ centers,
    const float* __restrict__ widths, const unsigned* __restrict__ packed,
    float* __restrict__ out_norm)
{
    __shared__ float s_z[64];
    __shared__ float s_z2[8][16];
    __shared__ float s_z4[4 * 256];
    __shared__ float s_red[8];
    const int b = blockIdx.x, tid = threadIdx.x;

    if (tid < 64) {
        int d = tid >> 2;
        float xv = x[b * D + d];
        float c = centers[tid], w = widths[tid];
        float diff = xv - c;
        s_z[tid] = 1e-9f - diff * diff / (2.0f * w * w);
    }
    __syncthreads();
    if (tid < 128) {   // pair tables: pair p = dims (2p, 2p+1)
        int p = tid >> 4, i = tid & 15;
        s_z2[p][i] = s_z[p * 8 + (i & 3)] + s_z[p * 8 + 4 + ((i >> 2) & 3)];
    }
    __syncthreads();
#pragma unroll
    for (int q = 0; q < 4; ++q)   // quad q = pairs (2q, 2q+1)
        s_z4[q * 256 + tid] = s_z2[2 * q][tid & 15] + s_z2[2 * q + 1][(tid >> 4) & 15];
    __syncthreads();

    float f[4], lsum = 0.0f;
#pragma unroll
    for (int j = 0; j < 4; ++j) {
        unsigned w = packed[tid + 256 * j];
        float s = s_z4[w & 255] + s_z4[256 + ((w >> 8) & 255)]
                + s_z4[512 + ((w >> 16) & 255)] + s_z4[768 + (w >> 24)];
        f[j] = __expf(s);
        lsum += f[j];
    }
#pragma unroll
    for (int off = 1; off < 64; off <<= 1) lsum += __shfl_xor(lsum, off, 64);
    const int lane = tid & 63, wid = tid >> 6;
    if (lane == 0) s_red[wid] = lsum;
    __syncthreads();
    if (tid == 0) {
        float tot = s_red[0] + s_red[1] + s_red[2] + s_red[3] + 1e-9f;
        s_red[4] = 1.0f / tot;
    }
    __syncthreads();
    const float inv = s_red[4];
#pragma unroll
    for (int j = 0; j < 4; ++j)
        out_norm[(size_t)b * R + tid + 256 * j] = f[j] * inv;
}

// ---------------- K2: MFMA GEMM with LDS-staged fragments (round-4 winner).
// Block = 16 rows x 176 cols, K-slice of 256 rules. 4 waves split 11 n-tiles
// 3/3/3/2. A converted fp32->bf16 during staging. Atomic epilogue.
__global__ __launch_bounds__(256, 4) void yhat_kernel(
    const float* __restrict__ norm, const unsigned short* __restrict__ Bsw,
    const float* __restrict__ x, float* __restrict__ out_y)
{
    __shared__ unsigned short Bs[NT * 16 * BSTR];   // 25344 B (reused as Gs)
    __shared__ unsigned short As[BT * BSTR];        // 2304 B
    __shared__ float xe[BT * 17];

    const int tid = threadIdx.x;
    const int mt = blockIdx.x & 255;
    const int ks = blockIdx.x >> 8;
    const int bl0 = mt * BT;
    const int r_base = ks * RPB;

    for (int t = tid; t < BT * 17; t += 256) {      // 272 > 256: strided loop!
        int bl = t / 17, i = t - bl * 17;
        xe[t] = (i < 16) ? x[(size_t)(bl0 + bl) * D + i] : 1.0f;
    }

    const int lane = tid & 63, wv = tid >> 6;
    const int m_ = lane & 15, q_ = lane >> 4;
    const int nt0 = wv * 3;
    const int ntn = (wv == 3) ? 2 : 3;

    f32x4 acc[3];
    const f32x4 zf = {0.f, 0.f, 0.f, 0.f};
    acc[0] = zf; acc[1] = zf; acc[2] = zf;

    for (int c0 = 0; c0 < RPB; c0 += KC) {
        const int kabs = r_base + c0;
        __syncthreads();
        // stage B chunk: 176 cols x 64 k (128 B each) from pre-swizzled Bsw
        for (int t = tid; t < NP * 8; t += 256) {
            int row = t >> 3, seg = t & 7;
            *(short8*)&Bs[row * BSTR + seg * 8] =
                *(const short8*)&Bsw[row * R + kabs + seg * 8];
        }
        // stage A: 16 rows x 64 k, fp32 -> bf16 (exactly 256 float4 loads)
        {
            int row = tid >> 4, c4 = tid & 15;
            float4 v = *(const float4*)&norm[(size_t)(bl0 + row) * R + kabs + c4 * 4];
            ushort4 o;
            o.x = f2bf(v.x); o.y = f2bf(v.y); o.z = f2bf(v.z); o.w = f2bf(v.w);
            *(ushort4*)&As[row * BSTR + c4 * 4] = o;
        }
        __syncthreads();
#pragma unroll
        for (int kh = 0; kh < 2; ++kh) {
            short8 a = *(const short8*)&As[m_ * BSTR + kh * 32 + q_ * 8];
#pragma unroll
            for (int j = 0; j < 3; ++j) {
                if (j < ntn) {
                    int nt = nt0 + j;
                    short8 bfrag = *(const short8*)&Bs[(nt * 16 + m_) * BSTR + kh * 32 + q_ * 8];
                    acc[j] = __builtin_amdgcn_mfma_f32_16x16x32_bf16(a, bfrag, acc[j], 0, 0, 0);
                }
            }
        }
    }

    __syncthreads();
    float* Gs = (float*)Bs;    // 16 x 192 fp32 = 12288 B, fits in Bs
#pragma unroll
    for (int j = 0; j < 3; ++j) {
        if (j < ntn) {
            int nt = nt0 + j;
#pragma unroll
            for (int r = 0; r < 4; ++r)
                Gs[(q_ * 4 + r) * GSP + nt * 16 + m_] = acc[j][r];  // C/D: col=lane&15, row=quad*4+reg
        }
    }
    __syncthreads();
    if (tid < BT * NC) {
        int bl = tid / NC, c = tid - bl * NC;
        float y = 0.0f;
#pragma unroll
        for (int i = 0; i < 17; ++i)
            y += xe[bl * 17 + i] * Gs[bl * GSP + i * NC + c];
        atomicAdd(&out_y[(size_t)(bl0 + bl) * NC + c], y);
    }
}

extern "C" void kernel_launch(void* const* d_in, const int* in_sizes, int n_in,
                              void* d_out, int out_size, void* d_ws, size_t ws_size,
                              hipStream_t stream) {
    const float* x        = (const float*)d_in[0];
    const float* centers  = (const float*)d_in[1];
    const float* widths   = (const float*)d_in[2];
    const float* cons     = (const float*)d_in[3];
    const int*   rule_idx = (const int*)d_in[4];

    float* out      = (float*)d_out;
    float* out_y    = out;                                  // (4096,10)
    float* out_norm = out + (size_t)B * NC;                 // (4096,1024)
    float* out_xext = out + (size_t)B * NC + (size_t)B * R; // (4096,17)

    unsigned* packed     = (unsigned*)d_ws;                          // 4 KB
    unsigned short* Bsw  = (unsigned short*)((char*)d_ws + 4096);    // 352 KB

    prep_kernel<<<452, 256, 0, stream>>>(cons, rule_idx, x, packed, Bsw, out_y, out_xext);
    firing_kernel<<<B, 256, 0, stream>>>(x, centers, widths, packed, out_norm);
    yhat_kernel<<<(B / BT) * KSPLIT, 256, 0, stream>>>(out_norm, Bsw, x, out_y);
}